// Round 1
// baseline (918.376 us; speedup 1.0000x reference)
//
#include <hip/hip_runtime.h>

#define NF 64  // hidden width (both layers)

// ---------- degree / norm ----------
__global__ __launch_bounds__(256) void k_fill1(float* deg, int n) {
    int i = blockIdx.x * 256 + threadIdx.x;
    if (i < n) deg[i] = 1.0f;  // self-loop
}

__global__ __launch_bounds__(256) void k_count(const int* __restrict__ dst, float* deg, int E) {
    int e = blockIdx.x * 256 + threadIdx.x;
    if (e < E) atomicAdd(&deg[dst[e]], 1.0f);
}

__global__ __launch_bounds__(256) void k_rsqrt(float* dinv, int n) {
    int i = blockIdx.x * 256 + threadIdx.x;
    if (i < n) dinv[i] = rsqrtf(dinv[i]);
}

// ---------- dense GEMM: out[n][64] = act(X + bin) @ W ----------
// Block = 256 threads = 4 waves; each wave owns ROWS/4 rows.
// W[K][64] staged in LDS; x-row staged in wave-private LDS scratch.
template<int K, bool IN_ACT, int ROWS>
__global__ __launch_bounds__(256) void k_gemm(
    const float* __restrict__ X, const float* __restrict__ W,
    const float* __restrict__ bin, float* __restrict__ out, int n)
{
    __shared__ float Ws[K * NF];
    __shared__ float bs[K];
    __shared__ float xs[4][K];
    int t = threadIdx.x;
    for (int i = t; i < K * NF; i += 256) Ws[i] = W[i];
    if (IN_ACT) for (int i = t; i < K; i += 256) bs[i] = bin[i];
    __syncthreads();

    int wv = t >> 6, lane = t & 63;
    int row0 = blockIdx.x * ROWS + wv * (ROWS / 4);
    for (int r = 0; r < ROWS / 4; ++r) {
        int row = row0 + r;
        if (row >= n) return;
        for (int k = lane; k < K; k += 64) {
            float v = X[(size_t)row * K + k];
            if (IN_ACT) v = fmaxf(v + bs[k], 0.0f);
            xs[wv][k] = v;
        }
        // wave-synchronous LDS use (write+read by same wave; compiler inserts lgkmcnt)
        float acc = 0.0f;
#pragma unroll
        for (int k = 0; k < K; ++k) acc = fmaf(xs[wv][k], Ws[k * NF + lane], acc);
        out[(size_t)row * NF + lane] = acc;
    }
}

// ---------- self-loop init: agg[i][f] = h[i][f] * dinv[i]^2 ----------
__global__ __launch_bounds__(256) void k_selfloop(
    const float* __restrict__ H, const float* __restrict__ dinv,
    float* __restrict__ out, int n64)
{
    int i = blockIdx.x * 256 + threadIdx.x;
    if (i < n64) { float di = dinv[i >> 6]; out[i] = H[i] * di * di; }
}

// ---------- edge scatter: one wave per edge, per-lane atomics ----------
__global__ __launch_bounds__(256) void k_scatter(
    const float* __restrict__ H, const float* __restrict__ dinv,
    const int* __restrict__ src, const int* __restrict__ dst,
    float* __restrict__ out, int E)
{
    int e = blockIdx.x * 4 + (threadIdx.x >> 6);
    if (e >= E) return;
    int lane = threadIdx.x & 63;
    int s = src[e], d = dst[e];
    float norm = dinv[s] * dinv[d];
    atomicAdd(&out[(size_t)d * NF + lane], H[(size_t)s * NF + lane] * norm);
}

// ---------- decoder: out[i] = relu(agg[i] + b2) . Wd + bd ----------
__global__ __launch_bounds__(256) void k_decode(
    const float* __restrict__ A, const float* __restrict__ b2,
    const float* __restrict__ Wd, const float* __restrict__ bd,
    float* __restrict__ out, int n)
{
    int row = blockIdx.x * 4 + (threadIdx.x >> 6);
    if (row >= n) return;
    int lane = threadIdx.x & 63;
    float v = fmaxf(A[(size_t)row * NF + lane] + b2[lane], 0.0f) * Wd[lane];
#pragma unroll
    for (int o = 32; o > 0; o >>= 1) v += __shfl_xor(v, o, 64);
    if (lane == 0) out[row] = v + bd[0];
}

extern "C" void kernel_launch(void* const* d_in, const int* in_sizes, int n_in,
                              void* d_out, int out_size, void* d_ws, size_t ws_size,
                              hipStream_t stream) {
    const float* x  = (const float*)d_in[0];
    const int*   ei = (const int*)d_in[1];
    const float* W1 = (const float*)d_in[2];
    const float* b1 = (const float*)d_in[3];
    const float* W2 = (const float*)d_in[4];
    const float* b2 = (const float*)d_in[5];
    const float* Wd = (const float*)d_in[6];
    const float* bd = (const float*)d_in[7];
    float* out = (float*)d_out;

    int n = in_sizes[0] / 128;
    int E = in_sizes[1] / 2;
    const int* src = ei;
    const int* dst = ei + E;

    float* dinv = (float*)d_ws;
    float* bufH = dinv + n;                 // n*64 floats
    float* bufA = bufH + (size_t)n * NF;    // n*64 floats
    int n64 = n * NF;

    k_fill1<<<(n + 255) / 256, 256, 0, stream>>>(dinv, n);
    k_count<<<(E + 255) / 256, 256, 0, stream>>>(dst, dinv, E);
    k_rsqrt<<<(n + 255) / 256, 256, 0, stream>>>(dinv, n);

    // layer 1: h = x @ W1 ; agg = selfloop + scatter   (bias/relu deferred)
    k_gemm<128, false, 32><<<(n + 31) / 32, 256, 0, stream>>>(x, W1, nullptr, bufH, n);
    k_selfloop<<<(n64 + 255) / 256, 256, 0, stream>>>(bufH, dinv, bufA, n64);
    k_scatter<<<(E + 3) / 4, 256, 0, stream>>>(bufH, dinv, src, dst, bufA, E);

    // layer 2: h = relu(agg + b1) @ W2 ; agg = selfloop + scatter
    k_gemm<64, true, 32><<<(n + 31) / 32, 256, 0, stream>>>(bufA, W2, b1, bufH, n);
    k_selfloop<<<(n64 + 255) / 256, 256, 0, stream>>>(bufH, dinv, bufA, n64);
    k_scatter<<<(E + 3) / 4, 256, 0, stream>>>(bufH, dinv, src, dst, bufA, E);

    // decoder
    k_decode<<<(n + 3) / 4, 256, 0, stream>>>(bufA, b2, Wd, bd, out, n);
}

// Round 2
// 551.175 us; speedup vs baseline: 1.6662x; 1.6662x over previous
//
#include <hip/hip_runtime.h>

#define NF 64  // hidden width (both layers)

// =================== CSR build ===================

__global__ __launch_bounds__(256) void k_zero(int* p, int n) {
    int i = blockIdx.x * 256 + threadIdx.x;
    if (i < n) p[i] = 0;
}

__global__ __launch_bounds__(256) void k_hist(const int* __restrict__ dst, int* cnt, int E) {
    int e = blockIdx.x * 256 + threadIdx.x;
    if (e < E) atomicAdd(&cnt[dst[e]], 1);
}

__device__ inline int wave_incl_scan(int x, int lane) {
#pragma unroll
    for (int o = 1; o < 64; o <<= 1) { int y = __shfl_up(x, o, 64); if (lane >= o) x += y; }
    return x;
}

// 1024 elements per block (256 threads x 4)
__global__ __launch_bounds__(256) void k_scan_a(const int* __restrict__ in, int* __restrict__ out,
                                                int* __restrict__ bsums, int n) {
    int t = threadIdx.x, lane = t & 63, wv = t >> 6;
    int base = blockIdx.x * 1024 + t * 4;
    int v[4]; int s = 0;
#pragma unroll
    for (int k = 0; k < 4; ++k) { int i = base + k; int x = (i < n) ? in[i] : 0; v[k] = s; s += x; }
    int incl = wave_incl_scan(s, lane);
    __shared__ int ws[4];
    if (lane == 63) ws[wv] = incl;
    __syncthreads();
    int wofs = 0;
#pragma unroll
    for (int w = 0; w < 4; ++w) if (w < wv) wofs += ws[w];
    int texcl = wofs + incl - s;
#pragma unroll
    for (int k = 0; k < 4; ++k) { int i = base + k; if (i < n) out[i] = texcl + v[k]; }
    if (t == 255) bsums[blockIdx.x] = wofs + incl;
}

__global__ void k_scan_b(int* bsums, int nb) {
    if (threadIdx.x == 0 && blockIdx.x == 0) {
        int s = 0;
        for (int i = 0; i < nb; ++i) { int x = bsums[i]; bsums[i] = s; s += x; }
    }
}

// finalize row_ptr, copy to cursor, compute dinv = rsqrt(1 + in-degree)
__global__ __launch_bounds__(256) void k_scan_c(int* __restrict__ rp, const int* __restrict__ bsums,
                                                const int* __restrict__ cnt, int* __restrict__ cur,
                                                float* __restrict__ dinv, int n) {
    int i = blockIdx.x * 256 + threadIdx.x;
    if (i < n) {
        int v = rp[i] + bsums[i >> 10];
        rp[i] = v; cur[i] = v;
        dinv[i] = rsqrtf(1.0f + (float)cnt[i]);
    }
}

__global__ __launch_bounds__(256) void k_fill(const int* __restrict__ src, const int* __restrict__ dst,
                                              int* __restrict__ cur, int* __restrict__ col, int E) {
    int e = blockIdx.x * 256 + threadIdx.x;
    if (e < E) { int d = dst[e]; int p = atomicAdd(&cur[d], 1); col[p] = src[e]; }
}

// =================== dense GEMM: hs[n][64] = (act(X + bin) @ W) * dinv[row] ===================
template<int K, bool IN_ACT, int ROWS>
__global__ __launch_bounds__(256) void k_gemm(
    const float* __restrict__ X, const float* __restrict__ W,
    const float* __restrict__ bin, const float* __restrict__ dinv,
    float* __restrict__ out, int n)
{
    __shared__ float Ws[K * NF];
    __shared__ float bs[K];
    __shared__ float xs[4][K];
    int t = threadIdx.x;
    for (int i = t; i < K * NF; i += 256) Ws[i] = W[i];
    if (IN_ACT) for (int i = t; i < K; i += 256) bs[i] = bin[i];
    __syncthreads();

    int wv = t >> 6, lane = t & 63;
    int row0 = blockIdx.x * ROWS + wv * (ROWS / 4);
    for (int r = 0; r < ROWS / 4; ++r) {
        int row = row0 + r;
        if (row >= n) return;
        for (int k = lane; k < K; k += 64) {
            float v = X[(size_t)row * K + k];
            if (IN_ACT) v = fmaxf(v + bs[k], 0.0f);
            xs[wv][k] = v;
        }
        float acc = 0.0f;
#pragma unroll
        for (int k = 0; k < K; ++k) acc = fmaf(xs[wv][k], Ws[k * NF + lane], acc);
        out[(size_t)row * NF + lane] = acc * dinv[row];
    }
}

// =================== pull aggregation ===================
// agg[d] = dinv[d] * ( hs[d] + sum_{s in N_in(d)} hs[s] ),  hs = h * dinv
// row_end[d] == cursor[d] after fill (== row_ptr[d] + indeg[d])
__global__ __launch_bounds__(256) void k_pull(
    const float* __restrict__ hs, const float* __restrict__ dinv,
    const int* __restrict__ row_ptr, const int* __restrict__ row_end,
    const int* __restrict__ col, float* __restrict__ out, int n)
{
    int d = blockIdx.x * 4 + (threadIdx.x >> 6);
    if (d >= n) return;
    int lane = threadIdx.x & 63;
    int beg = row_ptr[d], end = row_end[d];
    float acc = hs[(size_t)d * NF + lane];
    for (int j0 = beg; j0 < end; j0 += 64) {
        int m = end - j0; if (m > 64) m = 64;
        int idx = (j0 + lane < end) ? col[j0 + lane] : 0;
        for (int k = 0; k < m; ++k) {
            int s = __shfl(idx, k, 64);
            acc += hs[(size_t)s * NF + lane];
        }
    }
    out[(size_t)d * NF + lane] = acc * dinv[d];
}

// =================== decoder ===================
__global__ __launch_bounds__(256) void k_decode(
    const float* __restrict__ A, const float* __restrict__ b2,
    const float* __restrict__ Wd, const float* __restrict__ bd,
    float* __restrict__ out, int n)
{
    int row = blockIdx.x * 4 + (threadIdx.x >> 6);
    if (row >= n) return;
    int lane = threadIdx.x & 63;
    float v = fmaxf(A[(size_t)row * NF + lane] + b2[lane], 0.0f) * Wd[lane];
#pragma unroll
    for (int o = 32; o > 0; o >>= 1) v += __shfl_xor(v, o, 64);
    if (lane == 0) out[row] = v + bd[0];
}

extern "C" void kernel_launch(void* const* d_in, const int* in_sizes, int n_in,
                              void* d_out, int out_size, void* d_ws, size_t ws_size,
                              hipStream_t stream) {
    const float* x  = (const float*)d_in[0];
    const int*   ei = (const int*)d_in[1];
    const float* W1 = (const float*)d_in[2];
    const float* b1 = (const float*)d_in[3];
    const float* W2 = (const float*)d_in[4];
    const float* b2 = (const float*)d_in[5];
    const float* Wd = (const float*)d_in[6];
    const float* bd = (const float*)d_in[7];
    float* out = (float*)d_out;

    int n = in_sizes[0] / 128;
    int E = in_sizes[1] / 2;
    const int* src = ei;
    const int* dst = ei + E;

    // workspace layout
    float* dinv   = (float*)d_ws;               // n
    float* bufH   = dinv + n;                   // 64n
    float* bufA   = bufH + (size_t)n * NF;      // 64n
    int*   counts = (int*)(bufA + (size_t)n * NF); // n
    int*   row_ptr = counts + n;                // n
    int*   cursor  = row_ptr + n;               // n
    int*   bsums   = cursor + n;                // up to 256
    int*   col     = bsums + 256;               // E

    int nb = (n + 1023) / 1024;

    // ---- CSR build (by dst) + dinv ----
    k_zero<<<(n + 255) / 256, 256, 0, stream>>>(counts, n);
    k_hist<<<(E + 255) / 256, 256, 0, stream>>>(dst, counts, E);
    k_scan_a<<<nb, 256, 0, stream>>>(counts, row_ptr, bsums, n);
    k_scan_b<<<1, 64, 0, stream>>>(bsums, nb);
    k_scan_c<<<(n + 255) / 256, 256, 0, stream>>>(row_ptr, bsums, counts, cursor, dinv, n);
    k_fill<<<(E + 255) / 256, 256, 0, stream>>>(src, dst, cursor, col, E);

    // ---- layer 1: hs = (x @ W1) * dinv ; agg = pull ----
    k_gemm<128, false, 32><<<(n + 31) / 32, 256, 0, stream>>>(x, W1, nullptr, dinv, bufH, n);
    k_pull<<<(n + 3) / 4, 256, 0, stream>>>(bufH, dinv, row_ptr, cursor, col, bufA, n);

    // ---- layer 2: hs = (relu(agg + b1) @ W2) * dinv ; agg = pull ----
    k_gemm<64, true, 32><<<(n + 31) / 32, 256, 0, stream>>>(bufA, W2, b1, dinv, bufH, n);
    k_pull<<<(n + 3) / 4, 256, 0, stream>>>(bufH, dinv, row_ptr, cursor, col, bufA, n);

    // ---- decoder ----
    k_decode<<<(n + 3) / 4, 256, 0, stream>>>(bufA, b2, Wd, bd, out, n);
}

// Round 3
// 546.929 us; speedup vs baseline: 1.6792x; 1.0078x over previous
//
#include <hip/hip_runtime.h>

#define NF 64  // hidden width (both layers)

// =================== small utilities ===================

__global__ __launch_bounds__(256) void k_zero(int* p, int n) {
    int i = blockIdx.x * 256 + threadIdx.x;
    if (i < n) p[i] = 0;
}

__device__ inline int wave_incl_scan(int x, int lane) {
#pragma unroll
    for (int o = 1; o < 64; o <<= 1) { int y = __shfl_up(x, o, 64); if (lane >= o) x += y; }
    return x;
}

// =================== bucketed CSR build ===================
// bucket(d) = d >> 6  (64 dst nodes per bucket)

// LDS-privatized bucket histogram; ~256 blocks -> 400k global atomics
__global__ __launch_bounds__(256) void k_bhist(const int* __restrict__ dst, int* __restrict__ bcnt,
                                               int E, int NB) {
    __shared__ int h[2048];
    for (int i = threadIdx.x; i < NB; i += 256) h[i] = 0;
    __syncthreads();
    for (int e = blockIdx.x * 256 + threadIdx.x; e < E; e += gridDim.x * 256)
        atomicAdd(&h[dst[e] >> 6], 1);
    __syncthreads();
    for (int i = threadIdx.x; i < NB; i += 256) if (h[i]) atomicAdd(&bcnt[i], h[i]);
}

// single-block exclusive scan over up to 2048 entries (256 threads x 8)
// writes ptr[i] (exclusive scan), cur[i] (copy), ptr[NB] = total. in-place safe.
__global__ __launch_bounds__(256) void k_scan_small(const int* __restrict__ cnt, int* __restrict__ ptr,
                                                    int* __restrict__ cur, int NB) {
    int t = threadIdx.x, lane = t & 63, wv = t >> 6;
    int base = t * 8;
    int local[8]; int s = 0;
#pragma unroll
    for (int k = 0; k < 8; ++k) { int i = base + k; int x = (i < NB) ? cnt[i] : 0; local[k] = s; s += x; }
    int incl = wave_incl_scan(s, lane);
    __shared__ int ws[4];
    if (lane == 63) ws[wv] = incl;
    __syncthreads();
    int wofs = 0;
#pragma unroll
    for (int w = 0; w < 4; ++w) if (w < wv) wofs += ws[w];
    int texcl = wofs + incl - s;
#pragma unroll
    for (int k = 0; k < 8; ++k) {
        int i = base + k;
        if (i < NB) { int v = texcl + local[k]; ptr[i] = v; cur[i] = v; }
    }
    if (t == 255) ptr[NB] = ws[0] + ws[1] + ws[2] + ws[3];
}

// scatter packed (src<<6)|(dst&63) into bucket regions (sequential per bucket -> L2-friendly)
__global__ __launch_bounds__(256) void k_pass1(const int* __restrict__ src, const int* __restrict__ dst,
                                               int* __restrict__ bcur, int* __restrict__ pairs, int E) {
    int e = blockIdx.x * 256 + threadIdx.x;
    if (e < E) {
        int s = src[e], d = dst[e];
        int p = atomicAdd(&bcur[d >> 6], 1);
        pairs[p] = (s << 6) | (d & 63);
    }
}

// per-bucket node histogram via LDS atomics -> dense counts write (no global atomics)
__global__ __launch_bounds__(256) void k_lhist(const int* __restrict__ bptr, const int* __restrict__ pairs,
                                               int* __restrict__ counts, int n) {
    __shared__ int h[64];
    int b = blockIdx.x;
    if (threadIdx.x < 64) h[threadIdx.x] = 0;
    __syncthreads();
    int beg = bptr[b], end = bptr[b + 1];
    for (int j = beg + threadIdx.x; j < end; j += 256) atomicAdd(&h[pairs[j] & 63], 1);
    __syncthreads();
    int node = (b << 6) + threadIdx.x;
    if (threadIdx.x < 64 && node < n) counts[node] = h[threadIdx.x];
}

// 1024 elements per block (256 threads x 4) — node-level scan stage A
__global__ __launch_bounds__(256) void k_scan_a(const int* __restrict__ in, int* __restrict__ out,
                                                int* __restrict__ bsums, int n) {
    int t = threadIdx.x, lane = t & 63, wv = t >> 6;
    int base = blockIdx.x * 1024 + t * 4;
    int v[4]; int s = 0;
#pragma unroll
    for (int k = 0; k < 4; ++k) { int i = base + k; int x = (i < n) ? in[i] : 0; v[k] = s; s += x; }
    int incl = wave_incl_scan(s, lane);
    __shared__ int ws[4];
    if (lane == 63) ws[wv] = incl;
    __syncthreads();
    int wofs = 0;
#pragma unroll
    for (int w = 0; w < 4; ++w) if (w < wv) wofs += ws[w];
    int texcl = wofs + incl - s;
#pragma unroll
    for (int k = 0; k < 4; ++k) { int i = base + k; if (i < n) out[i] = texcl + v[k]; }
    if (t == 255) bsums[blockIdx.x] = wofs + incl;
}

// finalize row_ptr; dinv = rsqrt(1 + in-degree)
__global__ __launch_bounds__(256) void k_scan_c(int* __restrict__ rp, const int* __restrict__ bsums,
                                                const int* __restrict__ cnt, float* __restrict__ dinv, int n) {
    int i = blockIdx.x * 256 + threadIdx.x;
    if (i < n) {
        rp[i] += bsums[i >> 10];
        dinv[i] = rsqrtf(1.0f + (float)cnt[i]);
    }
}

// per-bucket CSR placement via LDS cursors; col writes dense within bucket region
__global__ __launch_bounds__(256) void k_place(const int* __restrict__ bptr, const int* __restrict__ pairs,
                                               const int* __restrict__ row_ptr, int* __restrict__ col, int n) {
    __shared__ int cur[64];
    int b = blockIdx.x;
    int node = (b << 6) + threadIdx.x;
    if (threadIdx.x < 64) cur[threadIdx.x] = (node < n) ? row_ptr[node] : 0;
    __syncthreads();
    int beg = bptr[b], end = bptr[b + 1];
    for (int j = beg + threadIdx.x; j < end; j += 256) {
        int pk = pairs[j];
        int p = atomicAdd(&cur[pk & 63], 1);
        col[p] = pk >> 6;
    }
}

// =================== dense GEMM: hs[n][64] = (act(X + bin) @ W) * dinv[row] ===================
template<int K, bool IN_ACT, int ROWS>
__global__ __launch_bounds__(256) void k_gemm(
    const float* __restrict__ X, const float* __restrict__ W,
    const float* __restrict__ bin, const float* __restrict__ dinv,
    float* __restrict__ out, int n)
{
    __shared__ float Ws[K * NF];
    __shared__ float bs[K];
    __shared__ float xs[4][K];
    int t = threadIdx.x;
    for (int i = t; i < K * NF; i += 256) Ws[i] = W[i];
    if (IN_ACT) for (int i = t; i < K; i += 256) bs[i] = bin[i];
    __syncthreads();

    int wv = t >> 6, lane = t & 63;
    int row0 = blockIdx.x * ROWS + wv * (ROWS / 4);
    for (int r = 0; r < ROWS / 4; ++r) {
        int row = row0 + r;
        if (row >= n) return;
        for (int k = lane; k < K; k += 64) {
            float v = X[(size_t)row * K + k];
            if (IN_ACT) v = fmaxf(v + bs[k], 0.0f);
            xs[wv][k] = v;
        }
        float acc = 0.0f;
#pragma unroll
        for (int k = 0; k < K; ++k) acc = fmaf(xs[wv][k], Ws[k * NF + lane], acc);
        out[(size_t)row * NF + lane] = acc * dinv[row];
    }
}

// =================== pull aggregation ===================
// agg[d] = dinv[d] * ( hs[d] + sum_{s in N_in(d)} hs[s] ),  hs = h * dinv
// 8 independent gathers in flight per wave for latency hiding
__global__ __launch_bounds__(256) void k_pull(
    const float* __restrict__ hs, const float* __restrict__ dinv,
    const int* __restrict__ row_ptr, const int* __restrict__ cnt,
    const int* __restrict__ col, float* __restrict__ out, int n)
{
    int d = blockIdx.x * 4 + (threadIdx.x >> 6);
    if (d >= n) return;
    int lane = threadIdx.x & 63;
    int beg = row_ptr[d], end = beg + cnt[d];
    float acc = hs[(size_t)d * NF + lane];
    for (int j0 = beg; j0 < end; j0 += 64) {
        int m = end - j0; if (m > 64) m = 64;
        int idx = (j0 + lane < end) ? col[j0 + lane] : 0;
        int k = 0;
        for (; k + 8 <= m; k += 8) {
            int s0 = __shfl(idx, k,     64), s1 = __shfl(idx, k + 1, 64);
            int s2 = __shfl(idx, k + 2, 64), s3 = __shfl(idx, k + 3, 64);
            int s4 = __shfl(idx, k + 4, 64), s5 = __shfl(idx, k + 5, 64);
            int s6 = __shfl(idx, k + 6, 64), s7 = __shfl(idx, k + 7, 64);
            float v0 = hs[(size_t)s0 * NF + lane], v1 = hs[(size_t)s1 * NF + lane];
            float v2 = hs[(size_t)s2 * NF + lane], v3 = hs[(size_t)s3 * NF + lane];
            float v4 = hs[(size_t)s4 * NF + lane], v5 = hs[(size_t)s5 * NF + lane];
            float v6 = hs[(size_t)s6 * NF + lane], v7 = hs[(size_t)s7 * NF + lane];
            acc += ((v0 + v1) + (v2 + v3)) + ((v4 + v5) + (v6 + v7));
        }
        for (; k < m; ++k) {
            int s = __shfl(idx, k, 64);
            acc += hs[(size_t)s * NF + lane];
        }
    }
    out[(size_t)d * NF + lane] = acc * dinv[d];
}

// =================== decoder ===================
__global__ __launch_bounds__(256) void k_decode(
    const float* __restrict__ A, const float* __restrict__ b2,
    const float* __restrict__ Wd, const float* __restrict__ bd,
    float* __restrict__ out, int n)
{
    int row = blockIdx.x * 4 + (threadIdx.x >> 6);
    if (row >= n) return;
    int lane = threadIdx.x & 63;
    float v = fmaxf(A[(size_t)row * NF + lane] + b2[lane], 0.0f) * Wd[lane];
#pragma unroll
    for (int o = 32; o > 0; o >>= 1) v += __shfl_xor(v, o, 64);
    if (lane == 0) out[row] = v + bd[0];
}

extern "C" void kernel_launch(void* const* d_in, const int* in_sizes, int n_in,
                              void* d_out, int out_size, void* d_ws, size_t ws_size,
                              hipStream_t stream) {
    const float* x  = (const float*)d_in[0];
    const int*   ei = (const int*)d_in[1];
    const float* W1 = (const float*)d_in[2];
    const float* b1 = (const float*)d_in[3];
    const float* W2 = (const float*)d_in[4];
    const float* b2 = (const float*)d_in[5];
    const float* Wd = (const float*)d_in[6];
    const float* bd = (const float*)d_in[7];
    float* out = (float*)d_out;

    int n = in_sizes[0] / 128;
    int E = in_sizes[1] / 2;
    const int* src = ei;
    const int* dst = ei + E;

    int NB = (n + 63) >> 6;           // dst buckets of 64 nodes
    int nb = (n + 1023) / 1024;       // node-scan blocks

    // workspace layout (all 4-byte elems)
    float* dinv    = (float*)d_ws;                    // n
    float* bufH    = dinv + n;                        // 64n   (pairs aliases here during build)
    float* bufA    = bufH + (size_t)n * NF;           // 64n
    int*   counts  = (int*)(bufA + (size_t)n * NF);   // n
    int*   row_ptr = counts + n;                      // n
    int*   bsums   = row_ptr + n;                     // nb+1 (<=1028)
    int*   bptr    = bsums + 1028;                    // NB+1
    int*   bcur    = bptr + (NB + 1);                 // NB (doubles as bcnt; scan is in-place safe)
    int*   col     = bcur + NB;                       // E
    int*   pairs   = (int*)bufH;                      // E (lifetime: CSR build only)

    // ---- CSR build (by dst) + dinv ----
    k_zero<<<(NB + 255) / 256, 256, 0, stream>>>(bcur, NB);
    k_bhist<<<256, 256, 0, stream>>>(dst, bcur, E, NB);
    k_scan_small<<<1, 256, 0, stream>>>(bcur, bptr, bcur, NB);   // bptr = excl scan, bcur = cursor copy
    k_pass1<<<(E + 255) / 256, 256, 0, stream>>>(src, dst, bcur, pairs, E);
    k_lhist<<<NB, 256, 0, stream>>>(bptr, pairs, counts, n);
    k_scan_a<<<nb, 256, 0, stream>>>(counts, row_ptr, bsums, n);
    k_scan_small<<<1, 256, 0, stream>>>(bsums, bsums, bsums, nb); // in-place scan of block sums
    k_scan_c<<<(n + 255) / 256, 256, 0, stream>>>(row_ptr, bsums, counts, dinv, n);
    k_place<<<NB, 256, 0, stream>>>(bptr, pairs, row_ptr, col, n);

    // ---- layer 1: hs = (x @ W1) * dinv ; agg = pull ----  (pairs dead from here)
    k_gemm<128, false, 32><<<(n + 31) / 32, 256, 0, stream>>>(x, W1, nullptr, dinv, bufH, n);
    k_pull<<<(n + 3) / 4, 256, 0, stream>>>(bufH, dinv, row_ptr, counts, col, bufA, n);

    // ---- layer 2: hs = (relu(agg + b1) @ W2) * dinv ; agg = pull ----
    k_gemm<64, true, 32><<<(n + 31) / 32, 256, 0, stream>>>(bufA, W2, b1, dinv, bufH, n);
    k_pull<<<(n + 3) / 4, 256, 0, stream>>>(bufH, dinv, row_ptr, counts, col, bufA, n);

    // ---- decoder ----
    k_decode<<<(n + 3) / 4, 256, 0, stream>>>(bufA, b2, Wd, bd, out, n);
}